// Round 13
// baseline (237.359 us; speedup 1.0000x reference)
//
#include <hip/hip_runtime.h>
#include <math.h>

typedef unsigned short u16;
typedef unsigned int u32;
typedef short bf16x8 __attribute__((ext_vector_type(8)));
typedef short bf16x4 __attribute__((ext_vector_type(4)));
typedef float f32x4 __attribute__((ext_vector_type(4)));

#define MFMA(a, b, c) __builtin_amdgcn_mfma_f32_16x16x32_bf16(a, b, c, 0, 0, 0)

// exp2 folded scale: 1/temperature * log2(e) = 0.125 * 1.4426950408889634
#define SCALE_K 0.18033688011112043f

__device__ __forceinline__ float bf2f(u16 v) {
    union { float f; u32 u; } x;
    x.u = ((u32)v) << 16;
    return x.f;
}
__device__ __forceinline__ u16 f2bf(float f) {
    union { float f; u32 u; } x;
    x.f = f;
    u32 r = x.u + 0x7FFF + ((x.u >> 16) & 1);
    return (u16)(r >> 16);
}
__device__ __forceinline__ bf16x4 pk4(float a, float b, float c, float d) {
    union { u32 u[2]; bf16x4 v; } x;
    asm("v_cvt_pk_bf16_f32 %0, %1, %2" : "=v"(x.u[0]) : "v"(a), "v"(b));
    asm("v_cvt_pk_bf16_f32 %0, %1, %2" : "=v"(x.u[1]) : "v"(c), "v"(d));
    return x.v;
}

// ---------------- weight f32 -> bf16 conversion (3 x 512x512) ---------------------------
__global__ __launch_bounds__(256) void cvt_kernel(const float* __restrict__ s0,
                                                  const float* __restrict__ s1,
                                                  const float* __restrict__ s2,
                                                  u16* __restrict__ d0, u16* __restrict__ d1,
                                                  u16* __restrict__ d2) {
    int i = blockIdx.x * 256 + threadIdx.x;  // < 262144
    const float* s = (blockIdx.y == 0) ? s0 : ((blockIdx.y == 1) ? s1 : s2);
    u16* d = (blockIdx.y == 0) ? d0 : ((blockIdx.y == 1) ? d1 : d2);
    d[i] = f2bf(s[i]);
}

// ---------------- x f32 [b][512][3136] -> xT bf16 [b][3136][512] ------------------------
__global__ __launch_bounds__(256) void transpose_kernel(const float* __restrict__ x,
                                                        u16* __restrict__ xT) {
    __shared__ u16 tile[64][65];
    int b = blockIdx.z;
    int n0 = blockIdx.x * 64, c0 = blockIdx.y * 64;
    int j = threadIdx.x & 63, q = threadIdx.x >> 6;
    const float* xb = x + b * 512 * 3136;
#pragma unroll
    for (int it = 0; it < 16; ++it) {
        int r = q * 16 + it;
        tile[r][j] = f2bf(xb[(c0 + r) * 3136 + n0 + j]);
    }
    __syncthreads();
    u16* xTb = xT + b * 3136 * 512;
#pragma unroll
    for (int it = 0; it < 16; ++it) {
        int r = q * 16 + it;
        xTb[(n0 + r) * 512 + c0 + j] = tile[j][r];
    }
}

// ---------------- avgpool 3x3 s2 p1 from xT: thread t owns channels 2t, 2t+1 (u32) ------
__global__ __launch_bounds__(256) void pool_kernel(const u16* __restrict__ xT,
                                                   u16* __restrict__ pxT) {
    int n2 = blockIdx.x;        // 0..783
    int b = blockIdx.y;         // 0..1
    int t = threadIdx.x;
    int i = n2 / 28, jj = n2 % 28;
    float s0 = 0.f, s1 = 0.f;
    int cnt = 0;
    const u16* xb = xT + b * 3136 * 512;
#pragma unroll
    for (int dr = 0; dr < 3; dr++) {
        int r = 2 * i - 1 + dr;
        if (r < 0 || r >= 56) continue;
#pragma unroll
        for (int dc = 0; dc < 3; dc++) {
            int cc = 2 * jj - 1 + dc;
            if (cc < 0 || cc >= 56) continue;
            u32 pr = *(const u32*)(xb + (r * 56 + cc) * 512 + 2 * t);
            s0 += bf2f((u16)pr);
            s1 += bf2f((u16)(pr >> 16));
            cnt++;
        }
    }
    float invc = 1.0f / (float)cnt;
    u32 o = (u32)f2bf(s0 * invc) | ((u32)f2bf(s1 * invc) << 16);
    *(u32*)(pxT + (b * 784 + n2) * 512 + 2 * t) = o;
}

// ---------------- 32x32-per-wave MFMA core (2x2 frags): D = A * BT^T --------------------
// Round-12 postmortem: 64x64/wave tiles gave only 200/56-block grids (0.2-0.8 blocks/CU)
// -> latency-starved. 32x32/wave quadruples the grid; ~50 regs/wave -> high occupancy.
__device__ __forceinline__ void gemm_core32(const u16* __restrict__ A, int lda, int M,
                                            const u16* __restrict__ BT, int ldb, int Ncol,
                                            int K, int row0, int col0, f32x4 acc[2][2]) {
    int lane = threadIdx.x & 63;
    int lr = lane & 15, lg = lane >> 4;
    int ar[2], bc[2];
#pragma unroll
    for (int i = 0; i < 2; i++) {
        int r = row0 + i * 16 + lr;
        ar[i] = (r < M) ? r : (M - 1);
    }
#pragma unroll
    for (int j = 0; j < 2; j++) {
        int cj = col0 + j * 16 + lr;
        bc[j] = (cj < Ncol) ? cj : (Ncol - 1);
    }
#pragma unroll 2
    for (int k = 0; k < K; k += 32) {
        int ko = k + lg * 8;
        bf16x8 a0 = *(const bf16x8*)(A + ar[0] * lda + ko);
        bf16x8 a1 = *(const bf16x8*)(A + ar[1] * lda + ko);
        bf16x8 b0 = *(const bf16x8*)(BT + bc[0] * ldb + ko);
        bf16x8 b1 = *(const bf16x8*)(BT + bc[1] * ldb + ko);
        acc[0][0] = MFMA(a0, b0, acc[0][0]);
        acc[0][1] = MFMA(a0, b1, acc[0][1]);
        acc[1][0] = MFMA(a1, b0, acc[1][0]);
        acc[1][1] = MFMA(a1, b1, acc[1][1]);
    }
}

// ---------------- GEMM: D[n][oc] = xT[n][:] . W[oc][:] + bias, scatter to qk[bh][n][64] -
// 64x64 block (4 waves of 32x32). Pad rows [M, Npad) written ZERO.
__global__ __launch_bounds__(256) void gemm_qk(const u16* __restrict__ xT,
                                               const u16* __restrict__ W,
                                               const float* __restrict__ bias,
                                               u16* __restrict__ out, int M, int Npad,
                                               float oscale) {
    int b = blockIdx.z;
    int w = threadIdx.x >> 6;
    int row0 = blockIdx.y * 64 + (w >> 1) * 32;
    int col0 = blockIdx.x * 64 + (w & 1) * 32;
    f32x4 acc[2][2];
#pragma unroll
    for (int i = 0; i < 2; i++)
#pragma unroll
        for (int j = 0; j < 2; j++) acc[i][j] = (f32x4){0.f, 0.f, 0.f, 0.f};
    gemm_core32(xT + b * M * 512, 512, M, W, 512, 512, 512, row0, col0, acc);
    int lane = threadIdx.x & 63;
    int lr = lane & 15, lg = lane >> 4;
#pragma unroll
    for (int j = 0; j < 2; j++) {
        int oc = col0 + j * 16 + lr;
        float bs = bias[oc];
        int bh = b * 8 + (oc >> 6), dk = oc & 63;
        u16* op = out + (bh * Npad) * 64 + dk;
#pragma unroll
        for (int i = 0; i < 2; i++) {
#pragma unroll
            for (int r = 0; r < 4; r++) {
                int n = row0 + i * 16 + lg * 4 + r;
                if (n < M) op[n * 64] = f2bf((acc[i][j][r] + bs) * oscale);
                else if (n < Npad) op[n * 64] = 0;  // zero pad rows (masked in attn tail)
            }
        }
    }
}

// ---------------- GEMM: D[oc][n2] = W[oc][:] . pxT[n2][:] + bias, to vt[bh][64][800] ----
__global__ __launch_bounds__(256) void gemm_v(const u16* __restrict__ W,
                                              const u16* __restrict__ pxT,
                                              const float* __restrict__ bias,
                                              u16* __restrict__ vt) {
    int b = blockIdx.z;
    int w = threadIdx.x >> 6;
    int row0 = blockIdx.y * 64 + (w >> 1) * 32;
    int col0 = blockIdx.x * 64 + (w & 1) * 32;
    f32x4 acc[2][2];
#pragma unroll
    for (int i = 0; i < 2; i++)
#pragma unroll
        for (int j = 0; j < 2; j++) acc[i][j] = (f32x4){0.f, 0.f, 0.f, 0.f};
    gemm_core32(W, 512, 512, pxT + b * 784 * 512, 512, 784, 512, row0, col0, acc);
    int lane = threadIdx.x & 63;
    int lr = lane & 15, lg = lane >> 4;
#pragma unroll
    for (int i = 0; i < 2; i++) {
#pragma unroll
        for (int r = 0; r < 4; r++) {
            int oc = row0 + i * 16 + lg * 4 + r;
            float bs = bias[oc];
            u16* vp = vt + ((b * 8 + (oc >> 6)) * 64 + (oc & 63)) * 800;
#pragma unroll
            for (int j = 0; j < 2; j++) {
                int n2 = col0 + j * 16 + lr;
                if (n2 < 784) vp[n2] = f2bf(acc[i][j][r] + bs);
                else if (n2 < 800) vp[n2] = 0;  // zero pad: P_pad * 0 = 0 in PV
            }
        }
    }
}

// ---------------- pi stage 1: partial column sums of qt ---------------------------------
__global__ __launch_bounds__(256) void pi_stage1(const u16* __restrict__ qt,
                                                 float* __restrict__ part) {
    __shared__ float red[4][64];
    int chunk = blockIdx.x, bh = blockIdx.y;
    int t = threadIdx.x, dk = t & 63, seg = t >> 6;
    const u16* q = qt + (bh * 3136 + chunk * 112) * 64 + dk;
    float s = 0.f;
    for (int n = seg; n < 112; n += 4) s += bf2f(q[n * 64]);
    red[seg][dk] = s;
    __syncthreads();
    if (t < 64) part[(bh * 28 + chunk) * 64 + t] =
        red[0][t] + red[1][t] + red[2][t] + red[3][t];
}

// ---------------- pi stage 2: combine partials, dot mix_w, softmax ----------------------
__global__ __launch_bounds__(64) void pi_stage2(const float* __restrict__ part,
                                                const float* __restrict__ mix_w,
                                                float* __restrict__ pi) {
    int bh = blockIdx.x, lane = threadIdx.x;
    float bar = 0.f;
#pragma unroll
    for (int c = 0; c < 28; c++) bar += part[(bh * 28 + c) * 64 + lane];
    bar *= (1.0f / 3136.0f);
    float l0 = mix_w[lane] * bar;
    float l1 = mix_w[64 + lane] * bar;
#pragma unroll
    for (int d = 1; d < 64; d <<= 1) {
        l0 += __shfl_xor(l0, d);
        l1 += __shfl_xor(l1, d);
    }
    if (lane == 0) {
        float mx = fmaxf(l0, l1);
        float e0 = __expf(l0 - mx), e1 = __expf(l1 - mx);
        float inv = 1.0f / (e0 + e1);
        pi[bh * 2 + 0] = e0 * inv;
        pi[bh * 2 + 1] = e1 * inv;
    }
}

// ---------------- fused 2-mixture attention: mixture-split waves ------------------------
// Round-12 postmortem: occupancy stuck at 3 waves/SIMD (unified VGPR+AGPR ~170/wave from
// 2-mixture state). Split: wave w -> mixture m=w>>1, key-half w&1. Per-wave state halves
// (O 16 regs, qf 4, K 8) -> ~80 regs -> 5-6 waves/SIMD. Partials are plain sums (no
// running max), combined via 17KB LDS ([66] pad: 2-way max = free).
__global__ __launch_bounds__(256) void attn_kernel(const u16* __restrict__ qt,
                                                   const u16* __restrict__ kt,
                                                   const u16* __restrict__ vt,
                                                   const float* __restrict__ pi,
                                                   u16* __restrict__ ao) {
    __shared__ float ldsO[4][16][66];  // [wave][q][dv]
    __shared__ float ldsL[4][16];
    int w = threadIdx.x >> 6, lane = threadIdx.x & 63;
    int lr = lane & 15, lg = lane >> 4;
    int bh = blockIdx.x & 15;   // same head -> same XCD (mod 8): K/V L2-resident
    int qti = blockIdx.x >> 4;  // 0..195
    int qbase = qti * 16;
    int m = w >> 1, half = w & 1;
    const u16* qp = qt + (bh * 3136 + qbase) * 64;
    const u16* kbase = kt + bh * 800 * 64 + lr * 64 + m * 32 + lg * 8;
    const u16* vbase = vt + bh * 64 * 800 + lr * 800 + lg * 4;

    bf16x8 qf = *(const bf16x8*)(qp + lr * 64 + m * 32 + lg * 8);

    const f32x4 z4 = {0.f, 0.f, 0.f, 0.f};
    f32x4 O0 = z4, O1 = z4, O2 = z4, O3 = z4;
    float ls = 0.f;

    int cs = half ? 13 : 0, ce = half ? 25 : 13;
    for (int c = cs; c < ce; ++c) {
        int base = c * 32;
        bool tail = (c == 24);
        bf16x8 k0 = *(const bf16x8*)(kbase + base * 64);
        bf16x8 k1 = *(const bf16x8*)(kbase + (base + 16) * 64);
        bf16x4 va0 = *(const bf16x4*)(vbase + base);
        bf16x4 va1 = *(const bf16x4*)(vbase + base + 16 * 800);
        bf16x4 va2 = *(const bf16x4*)(vbase + base + 32 * 800);
        bf16x4 va3 = *(const bf16x4*)(vbase + base + 48 * 800);
        bf16x4 vb0 = *(const bf16x4*)(vbase + base + 16);
        bf16x4 vb1 = *(const bf16x4*)(vbase + base + 16 + 16 * 800);
        bf16x4 vb2 = *(const bf16x4*)(vbase + base + 16 + 32 * 800);
        bf16x4 vb3 = *(const bf16x4*)(vbase + base + 16 + 48 * 800);
        union { bf16x4 h[2]; bf16x8 w8; } vv0, vv1, vv2, vv3, pa;
        vv0.h[0] = va0; vv0.h[1] = vb0;
        vv1.h[0] = va1; vv1.h[1] = vb1;
        vv2.h[0] = va2; vv2.h[1] = vb2;
        vv3.h[0] = va3; vv3.h[1] = vb3;
        f32x4 s0 = MFMA(k0, qf, z4);
        f32x4 s1 = MFMA(k1, qf, z4);
        float p0 = __builtin_amdgcn_exp2f(s0[0]);
        float p1 = __builtin_amdgcn_exp2f(s0[1]);
        float p2 = __builtin_amdgcn_exp2f(s0[2]);
        float p3 = __builtin_amdgcn_exp2f(s0[3]);
        float p4 = __builtin_amdgcn_exp2f(s1[0]);
        float p5 = __builtin_amdgcn_exp2f(s1[1]);
        float p6 = __builtin_amdgcn_exp2f(s1[2]);
        float p7 = __builtin_amdgcn_exp2f(s1[3]);
        if (tail) { p4 = 0.f; p5 = 0.f; p6 = 0.f; p7 = 0.f; }  // keys 784..799
        ls += ((p0 + p1) + (p2 + p3)) + ((p4 + p5) + (p6 + p7));
        pa.h[0] = pk4(p0, p1, p2, p3);
        pa.h[1] = pk4(p4, p5, p6, p7);
        O0 = MFMA(pa.w8, vv0.w8, O0);
        O1 = MFMA(pa.w8, vv1.w8, O1);
        O2 = MFMA(pa.w8, vv2.w8, O2);
        O3 = MFMA(pa.w8, vv3.w8, O3);
    }

    // per-query partial row-sum: combine the 4 lane groups of this wave
    ls += __shfl_xor(ls, 16);
    ls += __shfl_xor(ls, 32);
    if (lane < 16) ldsL[w][lr] = ls;
    // partial O -> LDS: lane (lr,lg) holds q=lg*4+r, dv=t*16+lr
#pragma unroll
    for (int r = 0; r < 4; r++) {
        ldsO[w][lg * 4 + r][0 * 16 + lr] = O0[r];
        ldsO[w][lg * 4 + r][1 * 16 + lr] = O1[r];
        ldsO[w][lg * 4 + r][2 * 16 + lr] = O2[r];
        ldsO[w][lg * 4 + r][3 * 16 + lr] = O3[r];
    }
    __syncthreads();

    // combine: waves 0,1 = mixture 0 halves; waves 2,3 = mixture 1 halves
    float pi0 = pi[bh * 2], pi1 = pi[bh * 2 + 1];
    int col = threadIdx.x & 63, rg = threadIdx.x >> 6;
    int b = bh >> 3, h = bh & 7;
    u16* aop = ao + ((b * 3136 + qbase) * 512) + h * 64;
#pragma unroll
    for (int i = 0; i < 4; i++) {
        int q = rg * 4 + i;
        float l0 = ldsL[0][q] + ldsL[1][q];
        float l1 = ldsL[2][q] + ldsL[3][q];
        float o0 = ldsO[0][q][col] + ldsO[1][q][col];
        float o1 = ldsO[2][q][col] + ldsO[3][q][col];
        aop[q * 512 + col] = f2bf((pi0 / l0) * o0 + (pi1 / l1) * o1);
    }
}

// ---------------- final GEMM + BN + residual (f32 residual, FLOAT32 out) ----------------
__global__ __launch_bounds__(256) void gemm_out(const u16* __restrict__ W,
                                                const u16* __restrict__ aoT,
                                                const float* __restrict__ gamma,
                                                const float* __restrict__ beta,
                                                const float* __restrict__ xres,
                                                float* __restrict__ out) {
    int b = blockIdx.z;
    int w = threadIdx.x >> 6;
    int row0 = blockIdx.y * 64 + (w >> 1) * 32;
    int col0 = blockIdx.x * 64 + (w & 1) * 32;
    f32x4 acc[2][2];
#pragma unroll
    for (int i = 0; i < 2; i++)
#pragma unroll
        for (int j = 0; j < 2; j++) acc[i][j] = (f32x4){0.f, 0.f, 0.f, 0.f};
    gemm_core32(W, 512, 512, aoT + b * 3136 * 512, 512, 3136, 512, row0, col0, acc);
    const float inv = 0.99999500003749969f;  // 1/sqrt(1+1e-5)
    int lane = threadIdx.x & 63;
    int lr = lane & 15, lg = lane >> 4;
#pragma unroll
    for (int i = 0; i < 2; i++) {
#pragma unroll
        for (int r = 0; r < 4; r++) {
            int oc = row0 + i * 16 + lg * 4 + r;
            float g = gamma[oc] * inv;
            float bt = beta[oc];
            const float* xp = xres + (b * 512 + oc) * 3136;
            float* op = out + (b * 512 + oc) * 3136;
#pragma unroll
            for (int j = 0; j < 2; j++) {
                int n = col0 + j * 16 + lr;
                if (n < 3136) op[n] = acc[i][j][r] * g + bt + xp[n];
            }
        }
    }
}

extern "C" void kernel_launch(void* const* d_in, const int* in_sizes, int n_in,
                              void* d_out, int out_size, void* d_ws, size_t ws_size,
                              hipStream_t stream) {
    const float* x = (const float*)d_in[0];
    const float* w_qs = (const float*)d_in[1];
    const float* b_qs = (const float*)d_in[2];
    const float* w_vs = (const float*)d_in[3];
    const float* b_vs = (const float*)d_in[4];
    const float* mix_w = (const float*)d_in[5];
    const float* w_out = (const float*)d_in[6];
    const float* gamma = (const float*)d_in[7];
    const float* beta = (const float*)d_in[8];
    float* out = (float*)d_out;

    char* ws = (char*)d_ws;
    u16* xT = (u16*)(ws + 0);              // 2*3136*512*2 = 6,422,528
    u16* ao = (u16*)(ws + 0);              // ALIAS xT: xT dead before attn writes ao
    u16* pxT = (u16*)(ws + 6422528);       // 2*784*512*2  = 1,605,632
    u16* qt = (u16*)(ws + 8028160);        // 16*3136*64*2 = 6,422,528
    u16* kt = (u16*)(ws + 14450688);       // 16*800*64*2  = 1,638,400
    u16* vt = (u16*)(ws + 16089088);       // 16*64*800*2  = 1,638,400
    u16* wq_b = (u16*)(ws + 17727488);     // 524,288
    u16* wv_b = (u16*)(ws + 18251776);     // 524,288
    u16* wo_b = (u16*)(ws + 18776064);     // 524,288
    float* pi = (float*)(ws + 19300352);   // 128 bytes
    float* part = (float*)(ws + 19300480); // 114,688

    hipLaunchKernelGGL(cvt_kernel, dim3(1024, 3), dim3(256), 0, stream, w_qs, w_vs, w_out,
                       wq_b, wv_b, wo_b);
    hipLaunchKernelGGL(transpose_kernel, dim3(49, 8, 2), dim3(256), 0, stream, x, xT);
    hipLaunchKernelGGL(pool_kernel, dim3(784, 2), dim3(256), 0, stream, xT, pxT);
    hipLaunchKernelGGL(gemm_qk, dim3(8, 49, 2), dim3(256), 0, stream, xT, wq_b, b_qs, qt,
                       3136, 3136, 1.0f);
    hipLaunchKernelGGL(gemm_qk, dim3(8, 13, 2), dim3(256), 0, stream, pxT, wq_b, b_qs, kt,
                       784, 800, SCALE_K);
    hipLaunchKernelGGL(gemm_v, dim3(13, 8, 2), dim3(256), 0, stream, wv_b, pxT, b_vs, vt);
    hipLaunchKernelGGL(pi_stage1, dim3(28, 16), dim3(256), 0, stream, qt, part);
    hipLaunchKernelGGL(pi_stage2, dim3(16), dim3(64), 0, stream, part, mix_w, pi);
    hipLaunchKernelGGL(attn_kernel, dim3(3136), dim3(256), 0, stream, qt, kt, vt, pi, ao);
    hipLaunchKernelGGL(gemm_out, dim3(49, 8, 2), dim3(256), 0, stream, wo_b, ao, gamma,
                       beta, x, out);
}